// Round 1
// baseline (1126.495 us; speedup 1.0000x reference)
//
#include <hip/hip_runtime.h>
#include <math.h>

constexpr int B_ = 16, E_ = 256, NC_ = 8, Q_ = 40, H_ = 64, W_ = 64, HW_ = 4096;
constexpr int NH_ = 8, HD_ = 32, OF_ = 64, KC_ = 264;  // KC_ = E + NC
constexpr int CH_ = 4;                                 // attention key chunks

__device__ __forceinline__ float gelu_f(float x) {
  return 0.5f * x * (1.0f + erff(x * 0.70710678118654752f));
}

// ---------- q branch (DO_LN=true) / final projection (DO_LN=false) ----------
template<bool DO_LN>
__global__ __launch_bounds__(256)
void row_gemm256(const float* __restrict__ X, const float* __restrict__ g,
                 const float* __restrict__ bt, const float* __restrict__ Wm,
                 const float* __restrict__ bias, float* __restrict__ Y) {
  const int row = blockIdx.x;
  const int t = threadIdx.x;
  __shared__ float xs[E_];
  float x = X[(size_t)row * E_ + t];
  if constexpr (DO_LN) {
    __shared__ float rs[4], rs2[4];
    __shared__ float smean, srstd;
    float s = x, s2 = x * x;
    #pragma unroll
    for (int o = 32; o > 0; o >>= 1) { s += __shfl_down(s, o, 64); s2 += __shfl_down(s2, o, 64); }
    if ((t & 63) == 0) { rs[t >> 6] = s; rs2[t >> 6] = s2; }
    __syncthreads();
    if (t == 0) {
      float S = rs[0] + rs[1] + rs[2] + rs[3];
      float S2 = rs2[0] + rs2[1] + rs2[2] + rs2[3];
      float m = S * (1.0f / E_);
      smean = m;
      srstd = rsqrtf(S2 * (1.0f / E_) - m * m + 1e-5f);
    }
    __syncthreads();
    x = (x - smean) * srstd * g[t] + bt[t];
  }
  xs[t] = x;
  __syncthreads();
  float acc = bias[t];
  #pragma unroll 8
  for (int c = 0; c < E_; ++c) acc += xs[c] * Wm[(size_t)c * E_ + t];
  Y[(size_t)row * E_ + t] = acc;
}

// ---------- GEMM1: out[b,p,d] = gelu(sum_c xcat[b,c,p] * W[c,d] + bias[d]) ----------
// A is channel-major (transposed). 64x64 tile, KB=16, 256 thr, 4x4 micro.
__global__ __launch_bounds__(256)
void gemm1_gelu(const float* __restrict__ img, const float* __restrict__ msk,
                const float* __restrict__ Wm, const float* __restrict__ bias,
                float* __restrict__ out) {
  const int b = blockIdx.z;
  const int n0 = blockIdx.y * 64;
  const int m0 = blockIdx.x * 64;
  const int t = threadIdx.x;
  const int tm = t >> 4, tn = t & 15;
  __shared__ __align__(16) float As[16][68];
  __shared__ __align__(16) float Bs[16][64];
  float acc[4][4] = {};
  const float* Ai = img + (size_t)b * E_ * HW_;
  const float* Am = msk + (size_t)b * NC_ * HW_;
  const int lk = t >> 4;
  const int lm = (t & 15) * 4;
  for (int k0 = 0; k0 < KC_; k0 += 16) {
    const int k = k0 + lk;
    float4 av = make_float4(0.f, 0.f, 0.f, 0.f);
    if (k < E_)       av = *(const float4*)(Ai + (size_t)k * HW_ + m0 + lm);
    else if (k < KC_) av = *(const float4*)(Am + (size_t)(k - E_) * HW_ + m0 + lm);
    *(float4*)&As[lk][lm] = av;
    float4 bv = make_float4(0.f, 0.f, 0.f, 0.f);
    if (k < KC_) bv = *(const float4*)(Wm + (size_t)k * E_ + n0 + lm);
    *(float4*)&Bs[lk][lm] = bv;
    __syncthreads();
    #pragma unroll
    for (int kk = 0; kk < 16; ++kk) {
      const float4 a4 = *(const float4*)&As[kk][tm * 4];
      const float4 b4 = *(const float4*)&Bs[kk][tn * 4];
      const float aa[4] = {a4.x, a4.y, a4.z, a4.w};
      const float bb[4] = {b4.x, b4.y, b4.z, b4.w};
      #pragma unroll
      for (int i = 0; i < 4; ++i)
        #pragma unroll
        for (int j = 0; j < 4; ++j) acc[i][j] += aa[i] * bb[j];
    }
    __syncthreads();
  }
  const float4 bv4 = *(const float4*)&bias[n0 + tn * 4];
  const float bb2[4] = {bv4.x, bv4.y, bv4.z, bv4.w};
  #pragma unroll
  for (int i = 0; i < 4; ++i) {
    const int m = m0 + tm * 4 + i;
    float4 r;
    r.x = gelu_f(acc[i][0] + bb2[0]);
    r.y = gelu_f(acc[i][1] + bb2[1]);
    r.z = gelu_f(acc[i][2] + bb2[2]);
    r.w = gelu_f(acc[i][3] + bb2[3]);
    *(float4*)(out + ((size_t)b * HW_ + m) * E_ + n0 + tn * 4) = r;
  }
}

// ---------- row-major A GEMM: out[b,m,n] = sum_k A[b,m,k] W[k,n] + bias[n] ----------
__global__ __launch_bounds__(256)
void gemm_rm(const float* __restrict__ A, const float* __restrict__ Wm,
             const float* __restrict__ bias, float* __restrict__ out) {
  const int b = blockIdx.z;
  const int n0 = blockIdx.y * 64;
  const int m0 = blockIdx.x * 64;
  const int t = threadIdx.x;
  const int tm = t >> 4, tn = t & 15;
  __shared__ __align__(16) float As[16][68];
  __shared__ __align__(16) float Bs[16][64];
  float acc[4][4] = {};
  const int amm = t >> 2;
  const int akl = (t & 3) * 4;
  const int lk = t >> 4, lm = (t & 15) * 4;
  const float* Ab = A + ((size_t)b * HW_ + m0) * E_;
  for (int k0 = 0; k0 < E_; k0 += 16) {
    const float4 va = *(const float4*)(Ab + (size_t)amm * E_ + k0 + akl);
    As[akl + 0][amm] = va.x;
    As[akl + 1][amm] = va.y;
    As[akl + 2][amm] = va.z;
    As[akl + 3][amm] = va.w;
    *(float4*)&Bs[lk][lm] = *(const float4*)(Wm + (size_t)(k0 + lk) * E_ + n0 + lm);
    __syncthreads();
    #pragma unroll
    for (int kk = 0; kk < 16; ++kk) {
      const float4 a4 = *(const float4*)&As[kk][tm * 4];
      const float4 b4 = *(const float4*)&Bs[kk][tn * 4];
      const float aa[4] = {a4.x, a4.y, a4.z, a4.w};
      const float bb[4] = {b4.x, b4.y, b4.z, b4.w};
      #pragma unroll
      for (int i = 0; i < 4; ++i)
        #pragma unroll
        for (int j = 0; j < 4; ++j) acc[i][j] += aa[i] * bb[j];
    }
    __syncthreads();
  }
  const float4 bv4 = *(const float4*)&bias[n0 + tn * 4];
  const float bb2[4] = {bv4.x, bv4.y, bv4.z, bv4.w};
  #pragma unroll
  for (int i = 0; i < 4; ++i) {
    const int m = m0 + tm * 4 + i;
    float4 r;
    r.x = acc[i][0] + bb2[0];
    r.y = acc[i][1] + bb2[1];
    r.z = acc[i][2] + bb2[2];
    r.w = acc[i][3] + bb2[3];
    *(float4*)(out + ((size_t)b * HW_ + m) * E_ + n0 + tn * 4) = r;
  }
}

// ---------- per-pixel mean/rstd over E channels ----------
__global__ __launch_bounds__(256)
void rowstats(const float* __restrict__ X, float* __restrict__ mean, float* __restrict__ rstd) {
  const int row = blockIdx.x * 4 + (threadIdx.x >> 6);
  const int lane = threadIdx.x & 63;
  const float4 v = *(const float4*)(X + (size_t)row * E_ + lane * 4);
  float s = v.x + v.y + v.z + v.w;
  float s2 = v.x * v.x + v.y * v.y + v.z * v.z + v.w * v.w;
  #pragma unroll
  for (int o = 32; o > 0; o >>= 1) { s += __shfl_down(s, o, 64); s2 += __shfl_down(s2, o, 64); }
  if (lane == 0) {
    const float m = s * (1.0f / E_);
    mean[row] = m;
    rstd[row] = rsqrtf(s2 * (1.0f / E_) - m * m + 1e-5f);
  }
}

// ---------- depthwise 3x3 with on-the-fly LN ----------
__global__ __launch_bounds__(256)
void dwconv_ln(const float* __restrict__ X2, const float* __restrict__ mean,
               const float* __restrict__ rstd, const float* __restrict__ g2,
               const float* __restrict__ b2, const float* __restrict__ wgt,
               const float* __restrict__ cbias, float* __restrict__ out) {
  const int d = threadIdx.x;
  const int b = blockIdx.z, h = blockIdx.y;
  const int w0 = blockIdx.x * 16;
  float o[16];
  const float bias = cbias[d];
  #pragma unroll
  for (int j = 0; j < 16; ++j) o[j] = bias;
  const float gg = g2[d], bb = b2[d];
  #pragma unroll
  for (int ky = 0; ky < 3; ++ky) {
    const int hh = h + ky - 1;
    if (hh < 0 || hh >= H_) continue;
    const float w30 = wgt[(ky * 3 + 0) * E_ + d];
    const float w31 = wgt[(ky * 3 + 1) * E_ + d];
    const float w32 = wgt[(ky * 3 + 2) * E_ + d];
    const size_t rowp = (size_t)b * HW_ + hh * W_;
    #pragma unroll
    for (int i = -1; i <= 16; ++i) {
      const int ww = w0 + i;
      if (ww < 0 || ww >= W_) continue;
      const size_t p = rowp + ww;
      const float xl = (X2[p * E_ + d] - mean[p]) * rstd[p] * gg + bb;
      #pragma unroll
      for (int kx = 0; kx < 3; ++kx) {
        const int j = i - kx + 1;
        if (j >= 0 && j < 16) o[j] += xl * (kx == 0 ? w30 : (kx == 1 ? w31 : w32));
      }
    }
  }
  const size_t ob_ = (size_t)b * HW_ + h * W_ + w0;
  #pragma unroll
  for (int j = 0; j < 16; ++j) out[(ob_ + j) * E_ + d] = o[j];
}

// ---------- t_img / t_msk reductions ----------
__global__ __launch_bounds__(256)
void tvec_k(const float* __restrict__ img, const float* __restrict__ msk,
            const float* __restrict__ icw, const float* __restrict__ icb,
            const float* __restrict__ mcw, const float* __restrict__ mcb,
            float* __restrict__ timg, float* __restrict__ tmsk) {
  const int b = blockIdx.y;
  const int lane = threadIdx.x & 63;
  const int p = blockIdx.x * 64 + lane;
  const int seg = threadIdx.x >> 6;
  __shared__ float red[4][64];
  float s = 0.f;
  const float* ib = img + (size_t)b * E_ * HW_ + p;
  #pragma unroll 4
  for (int e = seg * 64; e < seg * 64 + 64; ++e) s += ib[(size_t)e * HW_] * icw[e];
  red[seg][lane] = s;
  __syncthreads();
  if (seg == 0) {
    float tot = red[0][lane] + red[1][lane] + red[2][lane] + red[3][lane] + icb[0];
    timg[(size_t)b * HW_ + p] = tot;
    float s2 = mcb[0];
    const float* mb = msk + (size_t)b * NC_ * HW_ + p;
    #pragma unroll
    for (int c = 0; c < NC_; ++c) s2 += mb[(size_t)c * HW_] * mcw[c];
    tmsk[(size_t)b * HW_ + p] = s2;
  }
}

// ---------- att_image / att_mask: [B,HW] @ [HW,OF] + bias ----------
__global__ __launch_bounds__(256)
void attvec_k(const float* __restrict__ timg, const float* __restrict__ tmsk,
              const float* __restrict__ ipw, const float* __restrict__ ipb,
              const float* __restrict__ mpw, const float* __restrict__ mpb,
              float* __restrict__ ai, float* __restrict__ am) {
  const int b = blockIdx.x;
  const int mat = blockIdx.y;
  const float* tv = mat ? tmsk : timg;
  const float* wp = mat ? mpw : ipw;
  const float* bp = mat ? mpb : ipb;
  float* op = mat ? am : ai;
  const int o = threadIdx.x & 63, seg = threadIdx.x >> 6;
  float s = 0.f;
  for (int p = seg * 1024; p < seg * 1024 + 1024; ++p)
    s += tv[(size_t)b * HW_ + p] * wp[(size_t)p * OF_ + o];
  __shared__ float red[4][64];
  red[seg][o] = s;
  __syncthreads();
  if (seg == 0) op[b * OF_ + o] = red[0][o] + red[1][o] + red[2][o] + red[3][o] + bp[o];
}

// ---------- flash-style attention partials, per (chunk, head, batch) ----------
__global__ __launch_bounds__(256)
void attn_part(const float* __restrict__ qbuf, const float* __restrict__ kbuf,
               const float* __restrict__ vbuf, const float* __restrict__ masks,
               const float* __restrict__ ai, const float* __restrict__ am,
               const float* __restrict__ cw, const float* __restrict__ cb,
               const float* __restrict__ alpha, const float* __restrict__ beta,
               float* __restrict__ pacc, float* __restrict__ pm, float* __restrict__ pl) {
  const int c = blockIdx.x, n = blockIdx.y, b = blockIdx.z;
  const int t = threadIdx.x;
  __shared__ float qs[40][32];
  __shared__ float kst[32][65];   // [d][pix], stride 65 -> conflict-free
  __shared__ float vst[32][65];
  __shared__ float ss[40][65];
  __shared__ float aish[64], amsh[64];
  __shared__ float m_s[40], l_s[40], sc_s[40], tm_s[40];
  for (int idx = t; idx < Q_ * HD_; idx += 256) {
    const int q = idx >> 5, d = idx & 31;
    qs[q][d] = qbuf[((size_t)b * Q_ + q) * E_ + n * HD_ + d];
  }
  if (t < 64) aish[t] = ai[b * OF_ + t];
  else if (t < 128) amsh[t - 64] = am[b * OF_ + (t - 64)];
  else if (t < 128 + Q_) { m_s[t - 128] = -1e30f; l_s[t - 128] = 0.f; }
  float accv[5] = {0.f, 0.f, 0.f, 0.f, 0.f};
  const int dd = t & 31, qh = t >> 5;   // PV mapping
  const int pix = t & 63, qg = t >> 6;  // score mapping
  const int spp = t >> 2, sd0 = (t & 3) * 8;  // staging mapping
  __syncthreads();
  const float scl = 0.17677669529663687f;  // 1/sqrt(32)
  for (int tile = 0; tile < 1024 / 64; ++tile) {
    const int p0 = c * 1024 + tile * 64;
    {
      const float* kp = kbuf + ((size_t)b * HW_ + p0 + spp) * E_ + n * HD_ + sd0;
      const float* vp = vbuf + ((size_t)b * HW_ + p0 + spp) * E_ + n * HD_ + sd0;
      const float4 k1 = *(const float4*)kp;
      const float4 k2 = *(const float4*)(kp + 4);
      const float4 v1 = *(const float4*)vp;
      const float4 v2 = *(const float4*)(vp + 4);
      kst[sd0 + 0][spp] = k1.x; kst[sd0 + 1][spp] = k1.y;
      kst[sd0 + 2][spp] = k1.z; kst[sd0 + 3][spp] = k1.w;
      kst[sd0 + 4][spp] = k2.x; kst[sd0 + 5][spp] = k2.y;
      kst[sd0 + 6][spp] = k2.z; kst[sd0 + 7][spp] = k2.w;
      vst[sd0 + 0][spp] = v1.x; vst[sd0 + 1][spp] = v1.y;
      vst[sd0 + 2][spp] = v1.z; vst[sd0 + 3][spp] = v1.w;
      vst[sd0 + 4][spp] = v2.x; vst[sd0 + 5][spp] = v2.y;
      vst[sd0 + 6][spp] = v2.z; vst[sd0 + 7][spp] = v2.w;
    }
    __syncthreads();
    {
      const int p = p0 + pix;
      const float albase = aish[p >> 6] * amsh[p & 63];
      const float al = alpha[p] * scl;
      const float be = beta[p] * scl;
      #pragma unroll
      for (int j = 0; j < 10; ++j) {
        const int q = qg * 10 + j;
        float s = 0.f;
        #pragma unroll
        for (int d = 0; d < HD_; ++d) s += qs[q][d] * kst[d][pix];
        const float mk = masks[((size_t)b * NC_ + (q / 5)) * HW_ + p];
        ss[q][pix] = (albase * cw[q] + cb[q]) * al + s * mk * be;
      }
    }
    __syncthreads();
    if (t < Q_) {
      float mx = m_s[t];
      #pragma unroll 8
      for (int px = 0; px < 64; ++px) mx = fmaxf(mx, ss[t][px]);
      tm_s[t] = mx;
    }
    __syncthreads();
    #pragma unroll
    for (int j = 0; j < 10; ++j) {
      const int q = qg * 10 + j;
      ss[q][pix] = __expf(ss[q][pix] - tm_s[q]);
    }
    __syncthreads();
    if (t < Q_) {
      float sum = 0.f;
      #pragma unroll 8
      for (int px = 0; px < 64; ++px) sum += ss[t][px];
      const float scale = __expf(m_s[t] - tm_s[t]);
      sc_s[t] = scale;
      l_s[t] = l_s[t] * scale + sum;
      m_s[t] = tm_s[t];
    }
    __syncthreads();
    #pragma unroll
    for (int j = 0; j < 5; ++j) {
      const int q = qh * 5 + j;
      float a = accv[j] * sc_s[q];
      #pragma unroll 8
      for (int px = 0; px < 64; ++px) a += ss[q][px] * vst[dd][px];
      accv[j] = a;
    }
    __syncthreads();
  }
  const size_t pb = (size_t)((b * NH_ + n) * CH_ + c) * Q_;
  #pragma unroll
  for (int j = 0; j < 5; ++j) pacc[(pb + qh * 5 + j) * HD_ + dd] = accv[j];
  if (t < Q_) { pm[pb + t] = m_s[t]; pl[pb + t] = l_s[t]; }
}

// ---------- combine chunk partials -> ctx[B,Q,E] ----------
__global__ __launch_bounds__(256)
void attn_comb(const float* __restrict__ pacc, const float* __restrict__ pm,
               const float* __restrict__ pl, float* __restrict__ ctx) {
  const int idx = blockIdx.x * 256 + threadIdx.x;
  const int e = idx & 255;
  const int r = idx >> 8;  // b*Q + q
  const int q = r % Q_;
  const int b = r / Q_;
  const int n = e >> 5, d = e & 31;
  const int base = (b * NH_ + n) * CH_;
  float M = -1e30f;
  #pragma unroll
  for (int cc = 0; cc < CH_; ++cc) M = fmaxf(M, pm[(size_t)(base + cc) * Q_ + q]);
  float L = 0.f, O = 0.f;
  #pragma unroll
  for (int cc = 0; cc < CH_; ++cc) {
    const size_t o2 = (size_t)(base + cc) * Q_ + q;
    const float w = __expf(pm[o2] - M);
    L += pl[o2] * w;
    O += pacc[o2 * HD_ + d] * w;
  }
  ctx[idx] = O / L;
}

extern "C" void kernel_launch(void* const* d_in, const int* in_sizes, int n_in,
                              void* d_out, int out_size, void* d_ws, size_t ws_size,
                              hipStream_t stream) {
  (void)in_sizes; (void)n_in; (void)out_size; (void)ws_size;
  const float* qp    = (const float*)d_in[0];
  const float* img   = (const float*)d_in[1];
  const float* msk   = (const float*)d_in[2];
  const float* masks = (const float*)d_in[3];
  const float* ln_g  = (const float*)d_in[4];
  const float* ln_b  = (const float*)d_in[5];
  const float* qw    = (const float*)d_in[6];
  const float* qb    = (const float*)d_in[7];
  const float* x1w   = (const float*)d_in[8];
  const float* x1b   = (const float*)d_in[9];
  const float* x2w   = (const float*)d_in[10];
  const float* x2b   = (const float*)d_in[11];
  const float* ln2g  = (const float*)d_in[12];
  const float* ln2b  = (const float*)d_in[13];
  const float* dww   = (const float*)d_in[14];
  const float* dwb   = (const float*)d_in[15];
  const float* kw    = (const float*)d_in[16];
  const float* kb    = (const float*)d_in[17];
  const float* vw    = (const float*)d_in[18];
  const float* vb    = (const float*)d_in[19];
  const float* icw   = (const float*)d_in[20];
  const float* icb   = (const float*)d_in[21];
  const float* mcw   = (const float*)d_in[22];
  const float* mcb   = (const float*)d_in[23];
  const float* ipw   = (const float*)d_in[24];
  const float* ipb   = (const float*)d_in[25];
  const float* mpw   = (const float*)d_in[26];
  const float* mpb   = (const float*)d_in[27];
  const float* cw    = (const float*)d_in[28];
  const float* cb    = (const float*)d_in[29];
  const float* alpha = (const float*)d_in[30];
  const float* beta  = (const float*)d_in[31];
  const float* ow    = (const float*)d_in[32];
  const float* ob    = (const float*)d_in[33];

  float* ws = (float*)d_ws;
  const size_t BIG = (size_t)B_ * HW_ * E_;  // 16.78M floats
  float* bufA  = ws;                 // x1 -> x_final
  float* bufB  = ws + BIG;           // x2 -> k
  float* bufC  = ws + 2 * BIG;       // v
  float* qbuf  = ws + 3 * BIG;
  float* meanb = qbuf + (size_t)B_ * Q_ * E_;
  float* rstdb = meanb + (size_t)B_ * HW_;
  float* timg  = rstdb + (size_t)B_ * HW_;
  float* tmsk  = timg + (size_t)B_ * HW_;
  float* aib   = tmsk + (size_t)B_ * HW_;
  float* amb   = aib + B_ * OF_;
  float* pacc  = amb + B_ * OF_;
  float* pmb   = pacc + (size_t)B_ * NH_ * CH_ * Q_ * HD_;
  float* plb   = pmb + (size_t)B_ * NH_ * CH_ * Q_;
  float* ctx   = plb + (size_t)B_ * NH_ * CH_ * Q_;

  // q branch: LN + Linear
  row_gemm256<true><<<dim3(B_ * Q_), dim3(256), 0, stream>>>(qp, ln_g, ln_b, qw, qb, qbuf);
  // x1 = gelu(concat(img,msk) @ xp1_w + b)
  gemm1_gelu<<<dim3(64, 4, B_), dim3(256), 0, stream>>>(img, msk, x1w, x1b, bufA);
  // x2 = x1 @ xp2_w + b
  gemm_rm<<<dim3(64, 4, B_), dim3(256), 0, stream>>>(bufA, x2w, x2b, bufB);
  // channel-LN stats per pixel
  rowstats<<<dim3(B_ * HW_ / 4), dim3(256), 0, stream>>>(bufB, meanb, rstdb);
  // depthwise 3x3 with fused LN
  dwconv_ln<<<dim3(4, 64, B_), dim3(256), 0, stream>>>(bufB, meanb, rstdb, ln2g, ln2b, dww, dwb, bufA);
  // k, v
  gemm_rm<<<dim3(64, 4, B_), dim3(256), 0, stream>>>(bufA, kw, kb, bufB);
  gemm_rm<<<dim3(64, 4, B_), dim3(256), 0, stream>>>(bufA, vw, vb, bufC);
  // class-attention bias vectors
  tvec_k<<<dim3(64, B_), dim3(256), 0, stream>>>(img, msk, icw, icb, mcw, mcb, timg, tmsk);
  attvec_k<<<dim3(B_, 2), dim3(256), 0, stream>>>(timg, tmsk, ipw, ipb, mpw, mpb, aib, amb);
  // attention partials + combine
  attn_part<<<dim3(CH_, NH_, B_), dim3(256), 0, stream>>>(qbuf, bufB, bufC, masks, aib, amb,
                                                          cw, cb, alpha, beta, pacc, pmb, plb);
  attn_comb<<<dim3(B_ * Q_ * E_ / 256), dim3(256), 0, stream>>>(pacc, pmb, plb, ctx);
  // final projection
  row_gemm256<false><<<dim3(B_ * Q_), dim3(256), 0, stream>>>(ctx, nullptr, nullptr, ow, ob, (float*)d_out);
}

// Round 2
// 353.732 us; speedup vs baseline: 3.1846x; 3.1846x over previous
//
#include <hip/hip_runtime.h>
#include <math.h>

constexpr int B_ = 16, E_ = 256, NC_ = 8, Q_ = 40, H_ = 64, W_ = 64, HW_ = 4096;
constexpr int NH_ = 8, HD_ = 32, OF_ = 64;
constexpr int CH_ = 4;             // attention key chunks
constexpr int KP1_ = 320;          // padded K for gemm1 (E+NC=264 -> 320)

typedef __attribute__((ext_vector_type(8))) unsigned short us8;
typedef __attribute__((ext_vector_type(8))) short s8b;     // bf16 MFMA frag
typedef __attribute__((ext_vector_type(4))) float f32x4;

__device__ __forceinline__ float gelu_f(float x) {
  return 0.5f * x * (1.0f + erff(x * 0.70710678118654752f));
}
__device__ __forceinline__ float bf2f(unsigned short u) {
  return __uint_as_float(((unsigned int)u) << 16);
}
__device__ __forceinline__ unsigned short f2bf(float f) {
  unsigned int u = __float_as_uint(f);
  u = u + 0x7fff + ((u >> 16) & 1);  // RNE
  return (unsigned short)(u >> 16);
}

// ---------- q branch (DO_LN=true) / final projection (DO_LN=false) ----------
template<bool DO_LN>
__global__ __launch_bounds__(256)
void row_gemm256(const float* __restrict__ X, const float* __restrict__ g,
                 const float* __restrict__ bt, const float* __restrict__ Wm,
                 const float* __restrict__ bias, float* __restrict__ Y) {
  const int row = blockIdx.x;
  const int t = threadIdx.x;
  __shared__ float xs[E_];
  float x = X[(size_t)row * E_ + t];
  if constexpr (DO_LN) {
    __shared__ float rs[4], rs2[4];
    __shared__ float smean, srstd;
    float s = x, s2 = x * x;
    #pragma unroll
    for (int o = 32; o > 0; o >>= 1) { s += __shfl_down(s, o, 64); s2 += __shfl_down(s2, o, 64); }
    if ((t & 63) == 0) { rs[t >> 6] = s; rs2[t >> 6] = s2; }
    __syncthreads();
    if (t == 0) {
      float S = rs[0] + rs[1] + rs[2] + rs[3];
      float S2 = rs2[0] + rs2[1] + rs2[2] + rs2[3];
      float m = S * (1.0f / E_);
      smean = m;
      srstd = rsqrtf(S2 * (1.0f / E_) - m * m + 1e-5f);
    }
    __syncthreads();
    x = (x - smean) * srstd * g[t] + bt[t];
  }
  xs[t] = x;
  __syncthreads();
  float acc = bias[t];
  #pragma unroll 8
  for (int c = 0; c < E_; ++c) acc += xs[c] * Wm[(size_t)c * E_ + t];
  Y[(size_t)row * E_ + t] = acc;
}

// ---------- weight prep: Wt[n][k] = W[k][n] as bf16, zero pad k>=K ----------
__global__ __launch_bounds__(256)
void wprep(const float* __restrict__ w1, const float* __restrict__ w2,
           const float* __restrict__ wk, const float* __restrict__ wv,
           unsigned short* __restrict__ o1, unsigned short* __restrict__ o2,
           unsigned short* __restrict__ ok, unsigned short* __restrict__ ov) {
  const int n = threadIdx.x;
  const int k = blockIdx.x;
  const int which = blockIdx.y;
  const float* src = which == 0 ? w1 : (which == 1 ? w2 : (which == 2 ? wk : wv));
  unsigned short* dst = which == 0 ? o1 : (which == 1 ? o2 : (which == 2 ? ok : ov));
  const int K = which == 0 ? 264 : 256;
  const int KP = which == 0 ? KP1_ : 256;
  if (k >= KP) return;
  float v = (k < K) ? src[(size_t)k * E_ + n] : 0.f;
  dst[(size_t)n * KP + k] = f2bf(v);
}

// ---------- xcatT: bf16 [B*HW][KP1] from channel-major img/msk ----------
__global__ __launch_bounds__(256)
void xcat_t(const float* __restrict__ img, const float* __restrict__ msk,
            unsigned short* __restrict__ out) {
  __shared__ float tile[64][65];
  const int t = threadIdx.x;
  const int p0 = blockIdx.x * 64;
  const int k0 = blockIdx.y * 64;
  const int b = blockIdx.z;
  const int kk = t >> 6, pl = t & 63;
  #pragma unroll
  for (int ki = 0; ki < 16; ++ki) {
    const int k = k0 + kk * 16 + ki;
    float v;
    if (k < 256)      v = img[((size_t)b * E_ + k) * HW_ + p0 + pl];
    else if (k < 264) v = msk[((size_t)b * NC_ + (k - 256)) * HW_ + p0 + pl];
    else              v = 0.f;
    tile[pl][kk * 16 + ki] = v;
  }
  __syncthreads();
  const int pr = t >> 2, ch = t & 3;
  unsigned short st[16];
  #pragma unroll
  for (int i = 0; i < 16; ++i) st[i] = f2bf(tile[pr][ch * 16 + i]);
  unsigned short* dst = out + ((size_t)b * HW_ + p0 + pr) * KP1_ + k0 + ch * 16;
  *(us8*)dst = *(const us8*)&st[0];
  *(us8*)(dst + 8) = *(const us8*)&st[8];
}

// ---------- bf16 MFMA GEMM: C[M,256] = A[M,KP]bf16 @ Wt[256,KP]^T + bias ----------
// EPI: 0 = gelu->bf16, 1 = ->bf16
template<int EPI>
__global__ __launch_bounds__(256)
void mgemm(const unsigned short* __restrict__ A, const unsigned short* __restrict__ Wt,
           const float* __restrict__ bias, unsigned short* __restrict__ outb, int KP) {
  __shared__ unsigned short As[128 * 72];
  __shared__ unsigned short Bs[128 * 72];
  const int t = threadIdx.x;
  const int m0 = blockIdx.x * 128, n0 = blockIdx.y * 128;
  const int w = t >> 6, lane = t & 63;
  const int srow = t >> 3, scol = (t & 7) * 8;   // staging: 32 rows/iter, 8x16B per row
  const unsigned short* Ab = A + (size_t)m0 * KP;
  const unsigned short* Bb = Wt + (size_t)n0 * KP;
  us8 ra[4], rb[4];
  const int nt = KP >> 6;
  {
    #pragma unroll
    for (int r = 0; r < 4; ++r) {
      ra[r] = *(const us8*)(Ab + (size_t)(r * 32 + srow) * KP + scol);
      rb[r] = *(const us8*)(Bb + (size_t)(r * 32 + srow) * KP + scol);
    }
  }
  f32x4 acc[4][4];
  #pragma unroll
  for (int i = 0; i < 4; ++i)
    #pragma unroll
    for (int j = 0; j < 4; ++j) acc[i][j] = (f32x4){0.f, 0.f, 0.f, 0.f};
  const int wm = (w & 1) * 64, wn = (w >> 1) * 64;
  const int fr = lane & 15, fg = lane >> 4;
  for (int kt = 0; kt < nt; ++kt) {
    __syncthreads();
    #pragma unroll
    for (int r = 0; r < 4; ++r) {
      *(us8*)&As[(r * 32 + srow) * 72 + scol] = ra[r];
      *(us8*)&Bs[(r * 32 + srow) * 72 + scol] = rb[r];
    }
    __syncthreads();
    if (kt + 1 < nt) {
      #pragma unroll
      for (int r = 0; r < 4; ++r) {
        ra[r] = *(const us8*)(Ab + (size_t)(r * 32 + srow) * KP + (kt + 1) * 64 + scol);
        rb[r] = *(const us8*)(Bb + (size_t)(r * 32 + srow) * KP + (kt + 1) * 64 + scol);
      }
    }
    #pragma unroll
    for (int ks = 0; ks < 2; ++ks) {
      s8b af[4], bf[4];
      #pragma unroll
      for (int mi = 0; mi < 4; ++mi)
        af[mi] = *(const s8b*)&As[(wm + mi * 16 + fr) * 72 + ks * 32 + fg * 8];
      #pragma unroll
      for (int ni = 0; ni < 4; ++ni)
        bf[ni] = *(const s8b*)&Bs[(wn + ni * 16 + fr) * 72 + ks * 32 + fg * 8];
      #pragma unroll
      for (int mi = 0; mi < 4; ++mi)
        #pragma unroll
        for (int ni = 0; ni < 4; ++ni)
          acc[mi][ni] = __builtin_amdgcn_mfma_f32_16x16x32_bf16(af[mi], bf[ni], acc[mi][ni], 0, 0, 0);
    }
  }
  float bv[4];
  #pragma unroll
  for (int ni = 0; ni < 4; ++ni) bv[ni] = bias[n0 + wn + ni * 16 + fr];
  #pragma unroll
  for (int mi = 0; mi < 4; ++mi)
    #pragma unroll
    for (int r = 0; r < 4; ++r) {
      const int row = m0 + wm + mi * 16 + fg * 4 + r;
      const size_t rb2 = (size_t)row * E_;
      #pragma unroll
      for (int ni = 0; ni < 4; ++ni) {
        const int col = n0 + wn + ni * 16 + fr;
        float v = acc[mi][ni][r] + bv[ni];
        if constexpr (EPI == 0) v = gelu_f(v);
        outb[rb2 + col] = f2bf(v);
      }
    }
}

// ---------- per-pixel mean/rstd over E channels (bf16 input) ----------
__global__ __launch_bounds__(256)
void rowstats(const unsigned short* __restrict__ X, float* __restrict__ mean,
              float* __restrict__ rstd) {
  const int row = blockIdx.x * 4 + (threadIdx.x >> 6);
  const int lane = threadIdx.x & 63;
  const uint2 u = *(const uint2*)(X + (size_t)row * E_ + lane * 4);
  float a = bf2f(u.x & 0xffff), b = bf2f(u.x >> 16);
  float c = bf2f(u.y & 0xffff), d = bf2f(u.y >> 16);
  float s = a + b + c + d;
  float s2 = a * a + b * b + c * c + d * d;
  #pragma unroll
  for (int o = 32; o > 0; o >>= 1) { s += __shfl_down(s, o, 64); s2 += __shfl_down(s2, o, 64); }
  if (lane == 0) {
    const float m = s * (1.0f / E_);
    mean[row] = m;
    rstd[row] = rsqrtf(s2 * (1.0f / E_) - m * m + 1e-5f);
  }
}

// ---------- depthwise 3x3 with on-the-fly LN, 4-row tile, bf16 in/out ----------
__global__ __launch_bounds__(256)
void dwconv_ln2(const unsigned short* __restrict__ X2, const float* __restrict__ mean,
                const float* __restrict__ rstd, const float* __restrict__ g2,
                const float* __restrict__ b2, const float* __restrict__ wgt,
                const float* __restrict__ cbias, unsigned short* __restrict__ out) {
  const int d = threadIdx.x;
  const int w0 = blockIdx.x * 16;
  const int h0 = blockIdx.y * 4;
  const int b = blockIdx.z;
  float wq[9];
  #pragma unroll
  for (int i = 0; i < 9; ++i) wq[i] = wgt[i * E_ + d];
  const float gg = g2[d], bb = b2[d], bias = cbias[d];
  float o[4][16];
  #pragma unroll
  for (int oy = 0; oy < 4; ++oy)
    #pragma unroll
    for (int j = 0; j < 16; ++j) o[oy][j] = bias;
  #pragma unroll
  for (int s = 0; s < 6; ++s) {
    const int hh = h0 - 1 + s;
    if (hh < 0 || hh >= H_) continue;
    const size_t rowb = (size_t)b * HW_ + hh * W_;
    float r[18];
    #pragma unroll
    for (int i = 0; i < 18; ++i) {
      const int ww = w0 + i - 1;
      if (ww >= 0 && ww < W_) {
        const size_t p = rowb + ww;
        const float x = bf2f(X2[p * E_ + d]);
        r[i] = (x - mean[p]) * rstd[p] * gg + bb;
      } else r[i] = 0.f;
    }
    #pragma unroll
    for (int ky = 0; ky < 3; ++ky) {
      const int oy = s - ky;
      if (oy < 0 || oy >= 4) continue;
      const float w_0 = wq[ky * 3], w_1 = wq[ky * 3 + 1], w_2 = wq[ky * 3 + 2];
      #pragma unroll
      for (int j = 0; j < 16; ++j)
        o[oy][j] += r[j] * w_0 + r[j + 1] * w_1 + r[j + 2] * w_2;
    }
  }
  #pragma unroll
  for (int oy = 0; oy < 4; ++oy) {
    const size_t ob_ = (size_t)b * HW_ + (h0 + oy) * W_ + w0;
    #pragma unroll
    for (int j = 0; j < 16; ++j) out[(ob_ + j) * E_ + d] = f2bf(o[oy][j]);
  }
}

// ---------- t_img / t_msk reductions ----------
__global__ __launch_bounds__(256)
void tvec_k(const float* __restrict__ img, const float* __restrict__ msk,
            const float* __restrict__ icw, const float* __restrict__ icb,
            const float* __restrict__ mcw, const float* __restrict__ mcb,
            float* __restrict__ timg, float* __restrict__ tmsk) {
  const int b = blockIdx.y;
  const int lane = threadIdx.x & 63;
  const int p = blockIdx.x * 64 + lane;
  const int seg = threadIdx.x >> 6;
  __shared__ float red[4][64];
  float s = 0.f;
  const float* ib = img + (size_t)b * E_ * HW_ + p;
  #pragma unroll 4
  for (int e = seg * 64; e < seg * 64 + 64; ++e) s += ib[(size_t)e * HW_] * icw[e];
  red[seg][lane] = s;
  __syncthreads();
  if (seg == 0) {
    float tot = red[0][lane] + red[1][lane] + red[2][lane] + red[3][lane] + icb[0];
    timg[(size_t)b * HW_ + p] = tot;
    float s2 = mcb[0];
    const float* mb = msk + (size_t)b * NC_ * HW_ + p;
    #pragma unroll
    for (int c = 0; c < NC_; ++c) s2 += mb[(size_t)c * HW_] * mcw[c];
    tmsk[(size_t)b * HW_ + p] = s2;
  }
}

// ---------- att_image / att_mask: [B,HW] @ [HW,OF] + bias ----------
__global__ __launch_bounds__(256)
void attvec_k(const float* __restrict__ timg, const float* __restrict__ tmsk,
              const float* __restrict__ ipw, const float* __restrict__ ipb,
              const float* __restrict__ mpw, const float* __restrict__ mpb,
              float* __restrict__ ai, float* __restrict__ am) {
  const int b = blockIdx.x;
  const int mat = blockIdx.y;
  const float* tv = mat ? tmsk : timg;
  const float* wp = mat ? mpw : ipw;
  const float* bp = mat ? mpb : ipb;
  float* op = mat ? am : ai;
  const int o = threadIdx.x & 63, seg = threadIdx.x >> 6;
  float s = 0.f;
  for (int p = seg * 1024; p < seg * 1024 + 1024; ++p)
    s += tv[(size_t)b * HW_ + p] * wp[(size_t)p * OF_ + o];
  __shared__ float red[4][64];
  red[seg][o] = s;
  __syncthreads();
  if (seg == 0) op[b * OF_ + o] = red[0][o] + red[1][o] + red[2][o] + red[3][o] + bp[o];
}

// ---------- flash-style attention partials (bf16 k/v), per (chunk, head, batch) ----------
__global__ __launch_bounds__(256)
void attn_part(const float* __restrict__ qbuf, const unsigned short* __restrict__ kbuf,
               const unsigned short* __restrict__ vbuf, const float* __restrict__ masks,
               const float* __restrict__ ai, const float* __restrict__ am,
               const float* __restrict__ cw, const float* __restrict__ cb,
               const float* __restrict__ alpha, const float* __restrict__ beta,
               float* __restrict__ pacc, float* __restrict__ pm, float* __restrict__ pl) {
  const int c = blockIdx.x, n = blockIdx.y, b = blockIdx.z;
  const int t = threadIdx.x;
  __shared__ float qs[40][32];
  __shared__ float kst[32][68];   // stride 68 -> 16B-aligned rows
  __shared__ float vst[32][68];
  __shared__ float ss[40][68];
  __shared__ float aish[64], amsh[64];
  __shared__ float m_s[40], l_s[40], sc_s[40], tm_s[40];
  for (int idx = t; idx < Q_ * HD_; idx += 256) {
    const int q = idx >> 5, d = idx & 31;
    qs[q][d] = qbuf[((size_t)b * Q_ + q) * E_ + n * HD_ + d];
  }
  if (t < 64) aish[t] = ai[b * OF_ + t];
  else if (t < 128) amsh[t - 64] = am[b * OF_ + (t - 64)];
  else if (t < 128 + Q_) { m_s[t - 128] = -1e30f; l_s[t - 128] = 0.f; }
  float accv[5] = {0.f, 0.f, 0.f, 0.f, 0.f};
  const int dd = t & 31, qh = t >> 5;        // PV mapping
  const int pix = t & 63, qg = t >> 6;       // score mapping
  const int spp = t >> 2, sd0 = (t & 3) * 8; // staging mapping
  __syncthreads();
  const float scl = 0.17677669529663687f;  // 1/sqrt(32)
  for (int tile = 0; tile < 1024 / 64; ++tile) {
    const int p0 = c * 1024 + tile * 64;
    {
      const unsigned short* kp = kbuf + ((size_t)b * HW_ + p0 + spp) * E_ + n * HD_ + sd0;
      const unsigned short* vp = vbuf + ((size_t)b * HW_ + p0 + spp) * E_ + n * HD_ + sd0;
      const uint4 kv = *(const uint4*)kp;
      const uint4 vv = *(const uint4*)vp;
      kst[sd0 + 0][spp] = bf2f(kv.x & 0xffff); kst[sd0 + 1][spp] = bf2f(kv.x >> 16);
      kst[sd0 + 2][spp] = bf2f(kv.y & 0xffff); kst[sd0 + 3][spp] = bf2f(kv.y >> 16);
      kst[sd0 + 4][spp] = bf2f(kv.z & 0xffff); kst[sd0 + 5][spp] = bf2f(kv.z >> 16);
      kst[sd0 + 6][spp] = bf2f(kv.w & 0xffff); kst[sd0 + 7][spp] = bf2f(kv.w >> 16);
      vst[sd0 + 0][spp] = bf2f(vv.x & 0xffff); vst[sd0 + 1][spp] = bf2f(vv.x >> 16);
      vst[sd0 + 2][spp] = bf2f(vv.y & 0xffff); vst[sd0 + 3][spp] = bf2f(vv.y >> 16);
      vst[sd0 + 4][spp] = bf2f(vv.z & 0xffff); vst[sd0 + 5][spp] = bf2f(vv.z >> 16);
      vst[sd0 + 6][spp] = bf2f(vv.w & 0xffff); vst[sd0 + 7][spp] = bf2f(vv.w >> 16);
    }
    __syncthreads();
    {
      const int p = p0 + pix;
      const float albase = aish[p >> 6] * amsh[p & 63];
      const float al = alpha[p] * scl;
      const float be = beta[p] * scl;
      float kq[32];
      #pragma unroll
      for (int d = 0; d < 32; ++d) kq[d] = kst[d][pix];
      #pragma unroll
      for (int j = 0; j < 10; ++j) {
        const int q = qg * 10 + j;
        float s = 0.f;
        #pragma unroll
        for (int d0 = 0; d0 < 32; d0 += 4) {
          const float4 qv = *(const float4*)&qs[q][d0];
          s += qv.x * kq[d0] + qv.y * kq[d0 + 1] + qv.z * kq[d0 + 2] + qv.w * kq[d0 + 3];
        }
        const float mk = masks[((size_t)b * NC_ + (q / 5)) * HW_ + p];
        ss[q][pix] = (albase * cw[q] + cb[q]) * al + s * mk * be;
      }
    }
    __syncthreads();
    if (t < Q_) {
      float mx = m_s[t];
      #pragma unroll
      for (int px = 0; px < 16; ++px) {
        const float4 v4 = *(const float4*)&ss[t][px * 4];
        mx = fmaxf(mx, fmaxf(fmaxf(v4.x, v4.y), fmaxf(v4.z, v4.w)));
      }
      tm_s[t] = mx;
    }
    __syncthreads();
    #pragma unroll
    for (int j = 0; j < 10; ++j) {
      const int q = qg * 10 + j;
      ss[q][pix] = __expf(ss[q][pix] - tm_s[q]);
    }
    __syncthreads();
    if (t < Q_) {
      float sum = 0.f;
      #pragma unroll
      for (int px = 0; px < 16; ++px) {
        const float4 v4 = *(const float4*)&ss[t][px * 4];
        sum += (v4.x + v4.y) + (v4.z + v4.w);
      }
      const float scale = __expf(m_s[t] - tm_s[t]);
      sc_s[t] = scale;
      l_s[t] = l_s[t] * scale + sum;
      m_s[t] = tm_s[t];
    }
    __syncthreads();
    #pragma unroll
    for (int c4 = 0; c4 < 4; ++c4) {
      float vv[16];
      #pragma unroll
      for (int i = 0; i < 4; ++i) {
        const float4 v4 = *(const float4*)&vst[dd][c4 * 16 + i * 4];
        vv[i * 4] = v4.x; vv[i * 4 + 1] = v4.y; vv[i * 4 + 2] = v4.z; vv[i * 4 + 3] = v4.w;
      }
      #pragma unroll
      for (int j = 0; j < 5; ++j) {
        const int q = qh * 5 + j;
        float a = (c4 == 0) ? accv[j] * sc_s[q] : accv[j];
        #pragma unroll
        for (int i = 0; i < 4; ++i) {
          const float4 s4 = *(const float4*)&ss[q][c4 * 16 + i * 4];
          a += s4.x * vv[i * 4] + s4.y * vv[i * 4 + 1] + s4.z * vv[i * 4 + 2] + s4.w * vv[i * 4 + 3];
        }
        accv[j] = a;
      }
    }
    __syncthreads();
  }
  const size_t pb = (size_t)((b * NH_ + n) * CH_ + c) * Q_;
  #pragma unroll
  for (int j = 0; j < 5; ++j) pacc[(pb + qh * 5 + j) * HD_ + dd] = accv[j];
  if (t < Q_) { pm[pb + t] = m_s[t]; pl[pb + t] = l_s[t]; }
}

// ---------- combine chunk partials -> ctx[B,Q,E] ----------
__global__ __launch_bounds__(256)
void attn_comb(const float* __restrict__ pacc, const float* __restrict__ pm,
               const float* __restrict__ pl, float* __restrict__ ctx) {
  const int idx = blockIdx.x * 256 + threadIdx.x;
  const int e = idx & 255;
  const int r = idx >> 8;
  const int q = r % Q_;
  const int b = r / Q_;
  const int n = e >> 5, d = e & 31;
  const int base = (b * NH_ + n) * CH_;
  float M = -1e30f;
  #pragma unroll
  for (int cc = 0; cc < CH_; ++cc) M = fmaxf(M, pm[(size_t)(base + cc) * Q_ + q]);
  float L = 0.f, O = 0.f;
  #pragma unroll
  for (int cc = 0; cc < CH_; ++cc) {
    const size_t o2 = (size_t)(base + cc) * Q_ + q;
    const float w = __expf(pm[o2] - M);
    L += pl[o2] * w;
    O += pacc[o2 * HD_ + d] * w;
  }
  ctx[idx] = O / L;
}

extern "C" void kernel_launch(void* const* d_in, const int* in_sizes, int n_in,
                              void* d_out, int out_size, void* d_ws, size_t ws_size,
                              hipStream_t stream) {
  (void)in_sizes; (void)n_in; (void)out_size; (void)ws_size;
  const float* qp    = (const float*)d_in[0];
  const float* img   = (const float*)d_in[1];
  const float* msk   = (const float*)d_in[2];
  const float* masks = (const float*)d_in[3];
  const float* ln_g  = (const float*)d_in[4];
  const float* ln_b  = (const float*)d_in[5];
  const float* qw    = (const float*)d_in[6];
  const float* qb    = (const float*)d_in[7];
  const float* x1w   = (const float*)d_in[8];
  const float* x1b   = (const float*)d_in[9];
  const float* x2w   = (const float*)d_in[10];
  const float* x2b   = (const float*)d_in[11];
  const float* ln2g  = (const float*)d_in[12];
  const float* ln2b  = (const float*)d_in[13];
  const float* dww   = (const float*)d_in[14];
  const float* dwb   = (const float*)d_in[15];
  const float* kw    = (const float*)d_in[16];
  const float* kb    = (const float*)d_in[17];
  const float* vw    = (const float*)d_in[18];
  const float* vb    = (const float*)d_in[19];
  const float* icw   = (const float*)d_in[20];
  const float* icb   = (const float*)d_in[21];
  const float* mcw   = (const float*)d_in[22];
  const float* mcb   = (const float*)d_in[23];
  const float* ipw   = (const float*)d_in[24];
  const float* ipb   = (const float*)d_in[25];
  const float* mpw   = (const float*)d_in[26];
  const float* mpb   = (const float*)d_in[27];
  const float* cw    = (const float*)d_in[28];
  const float* cb    = (const float*)d_in[29];
  const float* alpha = (const float*)d_in[30];
  const float* beta  = (const float*)d_in[31];
  const float* ow    = (const float*)d_in[32];
  const float* ob    = (const float*)d_in[33];

  char* wsb = (char*)d_ws;
  const size_t MB = 1024 * 1024;
  unsigned short* xcatT = (unsigned short*)(wsb);            // 40MB; later reused as xf
  unsigned short* x1    = (unsigned short*)(wsb + 42 * MB);  // 32MB; later reused as k
  unsigned short* x2    = (unsigned short*)(wsb + 76 * MB);  // 32MB; later reused as v
  unsigned short* xf    = xcatT;
  unsigned short* kbuf  = x1;
  unsigned short* vbuf  = x2;
  float* fb    = (float*)(wsb + 110 * MB);
  float* qbuf  = fb;                                   // 163840
  float* meanb = qbuf + (size_t)B_ * Q_ * E_;
  float* rstdb = meanb + (size_t)B_ * HW_;
  float* timg  = rstdb + (size_t)B_ * HW_;
  float* tmsk  = timg + (size_t)B_ * HW_;
  float* aib   = tmsk + (size_t)B_ * HW_;
  float* amb   = aib + B_ * OF_;
  float* pacc  = amb + B_ * OF_;
  float* pmb   = pacc + (size_t)B_ * NH_ * CH_ * Q_ * HD_;
  float* plb   = pmb + (size_t)B_ * NH_ * CH_ * Q_;
  float* ctx   = plb + (size_t)B_ * NH_ * CH_ * Q_;
  unsigned short* wt1 = (unsigned short*)(wsb + 118 * MB);   // 256*320
  unsigned short* wt2 = wt1 + 256 * KP1_;
  unsigned short* wtk = wt2 + 256 * 256;
  unsigned short* wtv = wtk + 256 * 256;

  // prep: weights transpose+cast, xcat transpose+cast
  wprep<<<dim3(KP1_, 4), dim3(256), 0, stream>>>(x1w, x2w, kw, vw, wt1, wt2, wtk, wtv);
  xcat_t<<<dim3(64, 5, B_), dim3(256), 0, stream>>>(img, msk, xcatT);
  // q branch: LN + Linear
  row_gemm256<true><<<dim3(B_ * Q_), dim3(256), 0, stream>>>(qp, ln_g, ln_b, qw, qb, qbuf);
  // x1 = gelu(xcat @ xp1_w + b)  [bf16 out]
  mgemm<0><<<dim3(512, 2), dim3(256), 0, stream>>>(xcatT, wt1, x1b, x1, KP1_);
  // x2 = x1 @ xp2_w + b  [bf16 out]
  mgemm<1><<<dim3(512, 2), dim3(256), 0, stream>>>(x1, wt2, x2b, x2, 256);
  // channel-LN stats per pixel
  rowstats<<<dim3(B_ * HW_ / 4), dim3(256), 0, stream>>>(x2, meanb, rstdb);
  // depthwise 3x3 with fused LN -> xf (reuses xcatT region)
  dwconv_ln2<<<dim3(4, 16, B_), dim3(256), 0, stream>>>(x2, meanb, rstdb, ln2g, ln2b, dww, dwb, xf);
  // k, v  [bf16 out]
  mgemm<1><<<dim3(512, 2), dim3(256), 0, stream>>>(xf, wtk, kb, kbuf, 256);
  mgemm<1><<<dim3(512, 2), dim3(256), 0, stream>>>(xf, wtv, vb, vbuf, 256);
  // class-attention bias vectors
  tvec_k<<<dim3(64, B_), dim3(256), 0, stream>>>(img, msk, icw, icb, mcw, mcb, timg, tmsk);
  attvec_k<<<dim3(B_, 2), dim3(256), 0, stream>>>(timg, tmsk, ipw, ipb, mpw, mpb, aib, amb);
  // attention partials + combine
  attn_part<<<dim3(CH_, NH_, B_), dim3(256), 0, stream>>>(qbuf, kbuf, vbuf, masks, aib, amb,
                                                          cw, cb, alpha, beta, pacc, pmb, plb);
  attn_comb<<<dim3(B_ * Q_ * E_ / 256), dim3(256), 0, stream>>>(pacc, pmb, plb, ctx);
  // final projection
  row_gemm256<false><<<dim3(B_ * Q_), dim3(256), 0, stream>>>(ctx, nullptr, nullptr, ow, ob, (float*)d_out);
}

// Round 4
// 289.293 us; speedup vs baseline: 3.8940x; 1.2227x over previous
//
#include <hip/hip_runtime.h>
#include <math.h>

constexpr int B_ = 16, E_ = 256, NC_ = 8, Q_ = 40, H_ = 64, W_ = 64, HW_ = 4096;
constexpr int NH_ = 8, HD_ = 32, OF_ = 64;
constexpr int KP1_ = 320;          // padded K for gemm1 (E+NC=264 -> 320)
constexpr int NPART_ = 16;         // attention partials per (b,head): 4 chunks x 4 waves

typedef __attribute__((ext_vector_type(8))) unsigned short us8;
typedef __attribute__((ext_vector_type(8))) short s8b;     // bf16 MFMA frag
typedef __attribute__((ext_vector_type(4))) float f32x4;

__device__ __forceinline__ float gelu_f(float x) {
  return 0.5f * x * (1.0f + erff(x * 0.70710678118654752f));
}
__device__ __forceinline__ float bf2f(unsigned short u) {
  return __uint_as_float(((unsigned int)u) << 16);
}
__device__ __forceinline__ unsigned short f2bf(float f) {
  unsigned int u = __float_as_uint(f);
  u = u + 0x7fff + ((u >> 16) & 1);  // RNE
  return (unsigned short)(u >> 16);
}

// ---------- q branch (DO_LN=true) / final projection (DO_LN=false) ----------
template<bool DO_LN>
__global__ __launch_bounds__(256)
void row_gemm256(const float* __restrict__ X, const float* __restrict__ g,
                 const float* __restrict__ bt, const float* __restrict__ Wm,
                 const float* __restrict__ bias, float* __restrict__ Y) {
  const int row = blockIdx.x;
  const int t = threadIdx.x;
  __shared__ float xs[E_];
  float x = X[(size_t)row * E_ + t];
  if constexpr (DO_LN) {
    __shared__ float rs[4], rs2[4];
    __shared__ float smean, srstd;
    float s = x, s2 = x * x;
    #pragma unroll
    for (int o = 32; o > 0; o >>= 1) { s += __shfl_down(s, o, 64); s2 += __shfl_down(s2, o, 64); }
    if ((t & 63) == 0) { rs[t >> 6] = s; rs2[t >> 6] = s2; }
    __syncthreads();
    if (t == 0) {
      float S = rs[0] + rs[1] + rs[2] + rs[3];
      float S2 = rs2[0] + rs2[1] + rs2[2] + rs2[3];
      float m = S * (1.0f / E_);
      smean = m;
      srstd = rsqrtf(S2 * (1.0f / E_) - m * m + 1e-5f);
    }
    __syncthreads();
    x = (x - smean) * srstd * g[t] + bt[t];
  }
  xs[t] = x;
  __syncthreads();
  float acc = bias[t];
  #pragma unroll 8
  for (int c = 0; c < E_; ++c) acc += xs[c] * Wm[(size_t)c * E_ + t];
  Y[(size_t)row * E_ + t] = acc;
}

// ---------- weight prep: Wt[n][k] = W[k][n] as bf16, zero pad k>=K ----------
__global__ __launch_bounds__(256)
void wprep(const float* __restrict__ w1, const float* __restrict__ w2,
           const float* __restrict__ wk, const float* __restrict__ wv,
           unsigned short* __restrict__ o1, unsigned short* __restrict__ o2,
           unsigned short* __restrict__ ok, unsigned short* __restrict__ ov) {
  const int n = threadIdx.x;
  const int k = blockIdx.x;
  const int which = blockIdx.y;
  const float* src = which == 0 ? w1 : (which == 1 ? w2 : (which == 2 ? wk : wv));
  unsigned short* dst = which == 0 ? o1 : (which == 1 ? o2 : (which == 2 ? ok : ov));
  const int K = which == 0 ? 264 : 256;
  const int KP = which == 0 ? KP1_ : 256;
  if (k >= KP) return;
  float v = (k < K) ? src[(size_t)k * E_ + n] : 0.f;
  dst[(size_t)n * KP + k] = f2bf(v);
}

// ---------- xcatT: bf16 [B*HW][KP1] from channel-major img/msk ----------
__global__ __launch_bounds__(256)
void xcat_t(const float* __restrict__ img, const float* __restrict__ msk,
            unsigned short* __restrict__ out) {
  __shared__ float tile[64][65];
  const int t = threadIdx.x;
  const int p0 = blockIdx.x * 64;
  const int k0 = blockIdx.y * 64;
  const int b = blockIdx.z;
  const int kk = t >> 6, pl = t & 63;
  #pragma unroll
  for (int ki = 0; ki < 16; ++ki) {
    const int k = k0 + kk * 16 + ki;
    float v;
    if (k < 256)      v = img[((size_t)b * E_ + k) * HW_ + p0 + pl];
    else if (k < 264) v = msk[((size_t)b * NC_ + (k - 256)) * HW_ + p0 + pl];
    else              v = 0.f;
    tile[pl][kk * 16 + ki] = v;
  }
  __syncthreads();
  const int pr = t >> 2, ch = t & 3;
  unsigned short st[16];
  #pragma unroll
  for (int i = 0; i < 16; ++i) st[i] = f2bf(tile[pr][ch * 16 + i]);
  unsigned short* dst = out + ((size_t)b * HW_ + p0 + pr) * KP1_ + k0 + ch * 16;
  *(us8*)dst = *(const us8*)&st[0];
  *(us8*)(dst + 8) = *(const us8*)&st[8];
}

// ---------- bf16 MFMA GEMM: C[M,256] = A[M,KP]bf16 @ Wt[256,KP]^T + bias ----------
template<int EPI>
__global__ __launch_bounds__(256)
void mgemm(const unsigned short* __restrict__ A, const unsigned short* __restrict__ Wt,
           const float* __restrict__ bias, unsigned short* __restrict__ outb, int KP) {
  __shared__ unsigned short As[128 * 72];
  __shared__ unsigned short Bs[128 * 72];
  const int t = threadIdx.x;
  const int m0 = blockIdx.x * 128, n0 = blockIdx.y * 128;
  const int w = t >> 6, lane = t & 63;
  const int srow = t >> 3, scol = (t & 7) * 8;
  const unsigned short* Ab = A + (size_t)m0 * KP;
  const unsigned short* Bb = Wt + (size_t)n0 * KP;
  us8 ra[4], rb[4];
  const int nt = KP >> 6;
  {
    #pragma unroll
    for (int r = 0; r < 4; ++r) {
      ra[r] = *(const us8*)(Ab + (size_t)(r * 32 + srow) * KP + scol);
      rb[r] = *(const us8*)(Bb + (size_t)(r * 32 + srow) * KP + scol);
    }
  }
  f32x4 acc[4][4];
  #pragma unroll
  for (int i = 0; i < 4; ++i)
    #pragma unroll
    for (int j = 0; j < 4; ++j) acc[i][j] = (f32x4){0.f, 0.f, 0.f, 0.f};
  const int wm = (w & 1) * 64, wn = (w >> 1) * 64;
  const int fr = lane & 15, fg = lane >> 4;
  for (int kt = 0; kt < nt; ++kt) {
    __syncthreads();
    #pragma unroll
    for (int r = 0; r < 4; ++r) {
      *(us8*)&As[(r * 32 + srow) * 72 + scol] = ra[r];
      *(us8*)&Bs[(r * 32 + srow) * 72 + scol] = rb[r];
    }
    __syncthreads();
    if (kt + 1 < nt) {
      #pragma unroll
      for (int r = 0; r < 4; ++r) {
        ra[r] = *(const us8*)(Ab + (size_t)(r * 32 + srow) * KP + (kt + 1) * 64 + scol);
        rb[r] = *(const us8*)(Bb + (size_t)(r * 32 + srow) * KP + (kt + 1) * 64 + scol);
      }
    }
    #pragma unroll
    for (int ks = 0; ks < 2; ++ks) {
      s8b af[4], bf[4];
      #pragma unroll
      for (int mi = 0; mi < 4; ++mi)
        af[mi] = *(const s8b*)&As[(wm + mi * 16 + fr) * 72 + ks * 32 + fg * 8];
      #pragma unroll
      for (int ni = 0; ni < 4; ++ni)
        bf[ni] = *(const s8b*)&Bs[(wn + ni * 16 + fr) * 72 + ks * 32 + fg * 8];
      #pragma unroll
      for (int mi = 0; mi < 4; ++mi)
        #pragma unroll
        for (int ni = 0; ni < 4; ++ni)
          acc[mi][ni] = __builtin_amdgcn_mfma_f32_16x16x32_bf16(af[mi], bf[ni], acc[mi][ni], 0, 0, 0);
    }
  }
  float bv[4];
  #pragma unroll
  for (int ni = 0; ni < 4; ++ni) bv[ni] = bias[n0 + wn + ni * 16 + fr];
  #pragma unroll
  for (int mi = 0; mi < 4; ++mi)
    #pragma unroll
    for (int r = 0; r < 4; ++r) {
      const int row = m0 + wm + mi * 16 + fg * 4 + r;
      const size_t rb2 = (size_t)row * E_;
      #pragma unroll
      for (int ni = 0; ni < 4; ++ni) {
        const int col = n0 + wn + ni * 16 + fr;
        float v = acc[mi][ni][r] + bv[ni];
        if constexpr (EPI == 0) v = gelu_f(v);
        outb[rb2 + col] = f2bf(v);
      }
    }
}

// ---------- per-pixel mean/rstd over E channels (bf16 input) ----------
__global__ __launch_bounds__(256)
void rowstats(const unsigned short* __restrict__ X, float* __restrict__ mean,
              float* __restrict__ rstd) {
  const int row = blockIdx.x * 4 + (threadIdx.x >> 6);
  const int lane = threadIdx.x & 63;
  const uint2 u = *(const uint2*)(X + (size_t)row * E_ + lane * 4);
  float a = bf2f(u.x & 0xffff), b = bf2f(u.x >> 16);
  float c = bf2f(u.y & 0xffff), d = bf2f(u.y >> 16);
  float s = a + b + c + d;
  float s2 = a * a + b * b + c * c + d * d;
  #pragma unroll
  for (int o = 32; o > 0; o >>= 1) { s += __shfl_down(s, o, 64); s2 += __shfl_down(s2, o, 64); }
  if (lane == 0) {
    const float m = s * (1.0f / E_);
    mean[row] = m;
    rstd[row] = rsqrtf(s2 * (1.0f / E_) - m * m + 1e-5f);
  }
}

// ---------- depthwise 3x3 with on-the-fly LN, 4-row tile, bf16 in/out ----------
__global__ __launch_bounds__(256)
void dwconv_ln2(const unsigned short* __restrict__ X2, const float* __restrict__ mean,
                const float* __restrict__ rstd, const float* __restrict__ g2,
                const float* __restrict__ b2, const float* __restrict__ wgt,
                const float* __restrict__ cbias, unsigned short* __restrict__ out) {
  const int d = threadIdx.x;
  const int w0 = blockIdx.x * 16;
  const int h0 = blockIdx.y * 4;
  const int b = blockIdx.z;
  float wq[9];
  #pragma unroll
  for (int i = 0; i < 9; ++i) wq[i] = wgt[i * E_ + d];
  const float gg = g2[d], bb = b2[d], bias = cbias[d];
  float o[4][16];
  #pragma unroll
  for (int oy = 0; oy < 4; ++oy)
    #pragma unroll
    for (int j = 0; j < 16; ++j) o[oy][j] = bias;
  #pragma unroll
  for (int s = 0; s < 6; ++s) {
    const int hh = h0 - 1 + s;
    if (hh < 0 || hh >= H_) continue;
    const size_t rowb = (size_t)b * HW_ + hh * W_;
    float r[18];
    #pragma unroll
    for (int i = 0; i < 18; ++i) {
      const int ww = w0 + i - 1;
      if (ww >= 0 && ww < W_) {
        const size_t p = rowb + ww;
        const float x = bf2f(X2[p * E_ + d]);
        r[i] = (x - mean[p]) * rstd[p] * gg + bb;
      } else r[i] = 0.f;
    }
    #pragma unroll
    for (int ky = 0; ky < 3; ++ky) {
      const int oy = s - ky;
      if (oy < 0 || oy >= 4) continue;
      const float w_0 = wq[ky * 3], w_1 = wq[ky * 3 + 1], w_2 = wq[ky * 3 + 2];
      #pragma unroll
      for (int j = 0; j < 16; ++j)
        o[oy][j] += r[j] * w_0 + r[j + 1] * w_1 + r[j + 2] * w_2;
    }
  }
  #pragma unroll
  for (int oy = 0; oy < 4; ++oy) {
    const size_t ob_ = (size_t)b * HW_ + (h0 + oy) * W_ + w0;
    #pragma unroll
    for (int j = 0; j < 16; ++j) out[(ob_ + j) * E_ + d] = f2bf(o[oy][j]);
  }
}

// ---------- t_img / t_msk reductions ----------
__global__ __launch_bounds__(256)
void tvec_k(const float* __restrict__ img, const float* __restrict__ msk,
            const float* __restrict__ icw, const float* __restrict__ icb,
            const float* __restrict__ mcw, const float* __restrict__ mcb,
            float* __restrict__ timg, float* __restrict__ tmsk) {
  const int b = blockIdx.y;
  const int lane = threadIdx.x & 63;
  const int p = blockIdx.x * 64 + lane;
  const int seg = threadIdx.x >> 6;
  __shared__ float red[4][64];
  float s = 0.f;
  const float* ib = img + (size_t)b * E_ * HW_ + p;
  #pragma unroll 4
  for (int e = seg * 64; e < seg * 64 + 64; ++e) s += ib[(size_t)e * HW_] * icw[e];
  red[seg][lane] = s;
  __syncthreads();
  if (seg == 0) {
    float tot = red[0][lane] + red[1][lane] + red[2][lane] + red[3][lane] + icb[0];
    timg[(size_t)b * HW_ + p] = tot;
    float s2 = mcb[0];
    const float* mb = msk + (size_t)b * NC_ * HW_ + p;
    #pragma unroll
    for (int c = 0; c < NC_; ++c) s2 += mb[(size_t)c * HW_] * mcw[c];
    tmsk[(size_t)b * HW_ + p] = s2;
  }
}

// ---------- att_image / att_mask: [B,HW] @ [HW,OF] + bias ----------
__global__ __launch_bounds__(256)
void attvec_k(const float* __restrict__ timg, const float* __restrict__ tmsk,
              const float* __restrict__ ipw, const float* __restrict__ ipb,
              const float* __restrict__ mpw, const float* __restrict__ mpb,
              float* __restrict__ ai, float* __restrict__ am) {
  const int b = blockIdx.x;
  const int mat = blockIdx.y;
  const float* tv = mat ? tmsk : timg;
  const float* wp = mat ? mpw : ipw;
  const float* bp = mat ? mpb : ipb;
  float* op = mat ? am : ai;
  const int o = threadIdx.x & 63, seg = threadIdx.x >> 6;
  float s = 0.f;
  for (int p = seg * 1024; p < seg * 1024 + 1024; ++p)
    s += tv[(size_t)b * HW_ + p] * wp[(size_t)p * OF_ + o];
  __shared__ float red[4][64];
  red[seg][o] = s;
  __syncthreads();
  if (seg == 0) op[b * OF_ + o] = red[0][o] + red[1][o] + red[2][o] + red[3][o] + bp[o];
}

// ---------- attbias: A1[b][p] = ai[p>>6]*am[p&63]*alpha[p]*scl ; asd/bsd ----------
__global__ __launch_bounds__(256)
void attbias(const float* __restrict__ ai, const float* __restrict__ am,
             const float* __restrict__ alpha, const float* __restrict__ beta,
             float* __restrict__ A1, float* __restrict__ asd, float* __restrict__ bsd) {
  const int p = blockIdx.x * 256 + threadIdx.x;
  const int b = blockIdx.y;
  const float scl = 0.17677669529663687f;  // 1/sqrt(32)
  A1[(size_t)b * HW_ + p] = ai[b * OF_ + (p >> 6)] * am[b * OF_ + (p & 63)] * alpha[p] * scl;
  if (b == 0) {
    asd[p] = alpha[p] * scl;
    bsd[p] = beta[p] * scl;
  }
}

// ---------- MFMA flash attention partials ----------
// grid (4 chunks, NH, B), 4 waves/block; wave handles 256 pixels (4 tiles of 64)
__global__ __launch_bounds__(256)
void attn_mfma(const float* __restrict__ qbuf, const unsigned short* __restrict__ kbuf,
               const unsigned short* __restrict__ vbuf, const float* __restrict__ masks,
               const float* __restrict__ A1, const float* __restrict__ asd,
               const float* __restrict__ bsd, const float* __restrict__ cw,
               const float* __restrict__ cb,
               float* __restrict__ pacc, float* __restrict__ pm, float* __restrict__ pl) {
  const int ch = blockIdx.x, n = blockIdx.y, b = blockIdx.z;
  const int t = threadIdx.x, wid = t >> 6, lane = t & 63;
  const int c = lane & 15, g = lane >> 4;
  __shared__ __align__(16) unsigned short Pl[4][48 * 88];  // per-wave P, stride 88
  __shared__ __align__(16) unsigned short Vt[4][32 * 72];  // per-wave V^T, stride 72
  __shared__ __align__(16) float scw[4][64];               // per-wave rescale bcast

  const size_t bhw = (size_t)b * HW_;
  const int koff = n * HD_;
  const int pbase = ch * 1024 + wid * 256;

  // Q fragments (bf16), cw/cb, class per nt (q padded 40->48 with zeros)
  s8b qf[3];
  float cwq[3], cbq[3];
  int cls[3];
  #pragma unroll
  for (int nt = 0; nt < 3; ++nt) {
    const int q = nt * 16 + c;
    unsigned short tmp[8];
    if (q < Q_) {
      const float* qp = qbuf + ((size_t)b * Q_ + q) * E_ + koff + g * 8;
      const float4 f0 = *(const float4*)qp;
      const float4 f1 = *(const float4*)(qp + 4);
      tmp[0] = f2bf(f0.x); tmp[1] = f2bf(f0.y); tmp[2] = f2bf(f0.z); tmp[3] = f2bf(f0.w);
      tmp[4] = f2bf(f1.x); tmp[5] = f2bf(f1.y); tmp[6] = f2bf(f1.z); tmp[7] = f2bf(f1.w);
      cwq[nt] = cw[q]; cbq[nt] = cb[q];
    } else {
      #pragma unroll
      for (int i = 0; i < 8; ++i) tmp[i] = 0;
      cwq[nt] = 0.f; cbq[nt] = 0.f;
    }
    qf[nt] = *(const s8b*)tmp;
    cls[nt] = min(q / 5, NC_ - 1);
  }

  f32x4 acc_o[3][2];
  #pragma unroll
  for (int qt = 0; qt < 3; ++qt)
    #pragma unroll
    for (int dt = 0; dt < 2; ++dt) acc_o[qt][dt] = (f32x4){0.f, 0.f, 0.f, 0.f};
  float m_r[3] = {-1e30f, -1e30f, -1e30f};
  float l_r[3] = {0.f, 0.f, 0.f};

  for (int tile = 0; tile < 4; ++tile) {
    const int p0 = pbase + tile * 64;
    // K fragments direct from global: A[row=pix][k=d]
    s8b kf[4];
    #pragma unroll
    for (int mt = 0; mt < 4; ++mt)
      kf[mt] = *(const s8b*)(kbuf + (bhw + p0 + mt * 16 + c) * E_ + koff + g * 8);
    // V tile -> LDS transposed: Vt[d][p]
    #pragma unroll
    for (int cp = 0; cp < 4; ++cp) {
      const us8 vr = *(const us8*)(vbuf + (bhw + p0 + lane) * E_ + koff + cp * 8);
      #pragma unroll
      for (int i = 0; i < 8; ++i) Vt[wid][(cp * 8 + i) * 72 + lane] = vr[i];
    }
    // QK^T: S^T[pix][q]
    f32x4 sa[3][4];
    #pragma unroll
    for (int nt = 0; nt < 3; ++nt)
      #pragma unroll
      for (int mt = 0; mt < 4; ++mt)
        sa[nt][mt] = __builtin_amdgcn_mfma_f32_16x16x32_bf16(kf[mt], qf[nt],
                     (f32x4){0.f, 0.f, 0.f, 0.f}, 0, 0, 0);
    // per-p vectors
    f32x4 A1v[4], asv[4], bsv[4];
    #pragma unroll
    for (int mt = 0; mt < 4; ++mt) {
      const int pp = p0 + mt * 16 + g * 4;
      A1v[mt] = *(const f32x4*)(A1 + bhw + pp);
      asv[mt] = *(const f32x4*)(asd + pp);
      bsv[mt] = *(const f32x4*)(bsd + pp);
    }
    // epilogue per q-tile: bias+mask, online softmax, pack P to LDS
    #pragma unroll
    for (int nt = 0; nt < 3; ++nt) {
      const float* mrow = masks + ((size_t)b * NC_ + cls[nt]) * HW_;
      f32x4 att[4];
      #pragma unroll
      for (int mt = 0; mt < 4; ++mt) {
        const f32x4 mk = *(const f32x4*)(mrow + p0 + mt * 16 + g * 4);
        att[mt] = A1v[mt] * cwq[nt] + asv[mt] * cbq[nt] + sa[nt][mt] * mk * bsv[mt];
      }
      float mx = -1e30f;
      #pragma unroll
      for (int mt = 0; mt < 4; ++mt)
        mx = fmaxf(mx, fmaxf(fmaxf(att[mt][0], att[mt][1]), fmaxf(att[mt][2], att[mt][3])));
      mx = fmaxf(mx, __shfl_xor(mx, 16));
      mx = fmaxf(mx, __shfl_xor(mx, 32));
      const float newm = fmaxf(m_r[nt], mx);
      const float sc = __expf(m_r[nt] - newm);
      m_r[nt] = newm;
      float sum = 0.f;
      #pragma unroll
      for (int mt = 0; mt < 4; ++mt) {
        #pragma unroll
        for (int i = 0; i < 4; ++i) att[mt][i] = __expf(att[mt][i] - newm);
        sum += (att[mt][0] + att[mt][1]) + (att[mt][2] + att[mt][3]);
      }
      sum += __shfl_xor(sum, 16);
      sum += __shfl_xor(sum, 32);
      l_r[nt] = l_r[nt] * sc + sum;
      if (g == 0) scw[wid][nt * 16 + c] = sc;
      #pragma unroll
      for (int mt = 0; mt < 4; ++mt) {
        uint2 pw;
        pw.x = (unsigned int)f2bf(att[mt][0]) | ((unsigned int)f2bf(att[mt][1]) << 16);
        pw.y = (unsigned int)f2bf(att[mt][2]) | ((unsigned int)f2bf(att[mt][3]) << 16);
        *(uint2*)&Pl[wid][(nt * 16 + c) * 88 + mt * 16 + g * 4] = pw;
      }
    }
    __syncthreads();
    // rescale O
    f32x4 sc4[3];
    #pragma unroll
    for (int qt = 0; qt < 3; ++qt) sc4[qt] = *(const f32x4*)&scw[wid][qt * 16 + g * 4];
    #pragma unroll
    for (int qt = 0; qt < 3; ++qt)
      #pragma unroll
      for (int dt = 0; dt < 2; ++dt)
        #pragma unroll
        for (int r = 0; r < 4; ++r) acc_o[qt][dt][r] *= sc4[qt][r];
    // PV: O[q][d] += P[q][p] * Vt[d][p]
    #pragma unroll
    for (int ks = 0; ks < 2; ++ks) {
      s8b pf[3], vf[2];
      #pragma unroll
      for (int qt = 0; qt < 3; ++qt)
        pf[qt] = *(const s8b*)&Pl[wid][(qt * 16 + c) * 88 + ks * 32 + g * 8];
      #pragma unroll
      for (int dt = 0; dt < 2; ++dt)
        vf[dt] = *(const s8b*)&Vt[wid][(dt * 16 + c) * 72 + ks * 32 + g * 8];
      #pragma unroll
      for (int qt = 0; qt < 3; ++qt)
        #pragma unroll
        for (int dt = 0; dt < 2; ++dt)
          acc_o[qt][dt] = __builtin_amdgcn_mfma_f32_16x16x32_bf16(pf[qt], vf[dt], acc_o[qt][dt], 0, 0, 0);
    }
    __syncthreads();
  }
  // write partials
  const int pidx = ((b * NH_ + n) * NPART_) + ch * 4 + wid;
  #pragma unroll
  for (int qt = 0; qt < 3; ++qt)
    #pragma unroll
    for (int r = 0; r < 4; ++r) {
      const int q = qt * 16 + g * 4 + r;
      if (q < Q_) {
        #pragma unroll
        for (int dt = 0; dt < 2; ++dt)
          pacc[((size_t)pidx * Q_ + q) * HD_ + dt * 16 + c] = acc_o[qt][dt][r];
      }
    }
  if (g == 0) {
    #pragma unroll
    for (int nt = 0; nt < 3; ++nt) {
      const int q = nt * 16 + c;
      if (q < Q_) {
        pm[(size_t)pidx * Q_ + q] = m_r[nt];
        pl[(size_t)pidx * Q_ + q] = l_r[nt];
      }
    }
  }
}

// ---------- combine partials -> ctx[B,Q,E] ----------
__global__ __launch_bounds__(256)
void attn_comb(const float* __restrict__ pacc, const float* __restrict__ pm,
               const float* __restrict__ pl, float* __restrict__ ctx) {
  const int idx = blockIdx.x * 256 + threadIdx.x;
  const int e = idx & 255;
  const int r = idx >> 8;
  const int q = r % Q_;
  const int b = r / Q_;
  const int n = e >> 5, d = e & 31;
  const int base = (b * NH_ + n) * NPART_;
  float M = -1e30f;
  #pragma unroll
  for (int cc = 0; cc < NPART_; ++cc) M = fmaxf(M, pm[(size_t)(base + cc) * Q_ + q]);
  float L = 0.f, O = 0.f;
  #pragma unroll
  for (int cc = 0; cc < NPART_; ++cc) {
    const size_t o2 = (size_t)(base + cc) * Q_ + q;
    const float w = __expf(pm[o2] - M);
    L += pl[o2] * w;
    O += pacc[o2 * HD_ + d] * w;
  }
  ctx[idx] = O / L;
}

extern "C" void kernel_launch(void* const* d_in, const int* in_sizes, int n_in,
                              void* d_out, int out_size, void* d_ws, size_t ws_size,
                              hipStream_t stream) {
  (void)in_sizes; (void)n_in; (void)out_size; (void)ws_size;
  const float* qp    = (const float*)d_in[0];
  const float* img   = (const float*)d_in[1];
  const float* msk   = (const float*)d_in[2];
  const float* masks = (const float*)d_in[3];
  const float* ln_g  = (const float*)d_in[4];
  const float* ln_b  = (const float*)d_in[5];
  const float* qw    = (const float*)d_in[6];
  const float* qb    = (const float*)d_in[7];
  const float* x1w   = (const float*)d_in[8];
  const float* x1b   = (const float*)d_in[9];
  const float* x2w   = (const float*)d_in[10];
  const float* x2b   = (const float*)d_in[11];
  const float* ln2g  = (const float*)d_in[12];
  const float* ln2b  = (const float*)d_in[13];
  const float* dww   = (const float*)d_in[14];
  const float* dwb   = (const float*)d_in[15];
  const float* kw    = (const float*)d_in[16];
  const float* kb    = (const float*)d_in[17];
  const float* vw    = (const float*)d_in[18];
  const float* vb    = (const float*)d_in[19];
  const float* icw   = (const float*)d_in[20];
  const float* icb   = (const float*)d_in[21];
  const float* mcw   = (const float*)d_in[22];
  const float* mcb   = (const float*)d_in[23];
  const float* ipw   = (const float*)d_in[24];
  const float* ipb   = (const float*)d_in[25];
  const float* mpw   = (const float*)d_in[26];
  const float* mpb   = (const float*)d_in[27];
  const float* cw    = (const float*)d_in[28];
  const float* cb    = (const float*)d_in[29];
  const float* alpha = (const float*)d_in[30];
  const float* beta  = (const float*)d_in[31];
  const float* ow    = (const float*)d_in[32];
  const float* ob    = (const float*)d_in[33];

  char* wsb = (char*)d_ws;
  const size_t MB = 1024 * 1024;
  unsigned short* xcatT = (unsigned short*)(wsb);            // 42MB; later reused as xf
  unsigned short* x1    = (unsigned short*)(wsb + 42 * MB);  // 34MB; later reused as k
  unsigned short* x2    = (unsigned short*)(wsb + 76 * MB);  // 34MB; later reused as v
  unsigned short* xf    = xcatT;
  unsigned short* kbuf  = x1;
  unsigned short* vbuf  = x2;
  unsigned short* wt1 = (unsigned short*)(wsb + 110 * MB);
  unsigned short* wt2 = wt1 + 256 * KP1_;
  unsigned short* wtk = wt2 + 256 * 256;
  unsigned short* wtv = wtk + 256 * 256;
  float* fb    = (float*)(wsb + 112 * MB);
  float* qbuf  = fb;
  float* meanb = qbuf + (size_t)B_ * Q_ * E_;
  float* rstdb = meanb + (size_t)B_ * HW_;
  float* timg  = rstdb + (size_t)B_ * HW_;
  float* tmsk  = timg + (size_t)B_ * HW_;
  float* aib   = tmsk + (size_t)B_ * HW_;
  float* amb   = aib + B_ * OF_;
  float* A1b   = amb + B_ * OF_;
  float* asdb  = A1b + (size_t)B_ * HW_;
  float* bsdb  = asdb + HW_;
  float* pacc  = bsdb + HW_;
  float* pmb   = pacc + (size_t)B_ * NH_ * NPART_ * Q_ * HD_;
  float* plb   = pmb + (size_t)B_ * NH_ * NPART_ * Q_;
  float* ctx   = plb + (size_t)B_ * NH_ * NPART_ * Q_;

  // prep: weights transpose+cast, xcat transpose+cast
  wprep<<<dim3(KP1_, 4), dim3(256), 0, stream>>>(x1w, x2w, kw, vw, wt1, wt2, wtk, wtv);
  xcat_t<<<dim3(64, 5, B_), dim3(256), 0, stream>>>(img, msk, xcatT);
  // q branch: LN + Linear
  row_gemm256<true><<<dim3(B_ * Q_), dim3(256), 0, stream>>>(qp, ln_g, ln_b, qw, qb, qbuf);
  // x1 = gelu(xcat @ xp1_w + b)
  mgemm<0><<<dim3(512, 2), dim3(256), 0, stream>>>(xcatT, wt1, x1b, x1, KP1_);
  // x2 = x1 @ xp2_w + b
  mgemm<1><<<dim3(512, 2), dim3(256), 0, stream>>>(x1, wt2, x2b, x2, 256);
  // channel-LN stats per pixel
  rowstats<<<dim3(B_ * HW_ / 4), dim3(256), 0, stream>>>(x2, meanb, rstdb);
  // depthwise 3x3 with fused LN -> xf
  dwconv_ln2<<<dim3(4, 16, B_), dim3(256), 0, stream>>>(x2, meanb, rstdb, ln2g, ln2b, dww, dwb, xf);
  // k, v
  mgemm<1><<<dim3(512, 2), dim3(256), 0, stream>>>(xf, wtk, kb, kbuf, 256);
  mgemm<1><<<dim3(512, 2), dim3(256), 0, stream>>>(xf, wtv, vb, vbuf, 256);
  // class-attention bias vectors
  tvec_k<<<dim3(64, B_), dim3(256), 0, stream>>>(img, msk, icw, icb, mcw, mcb, timg, tmsk);
  attvec_k<<<dim3(B_, 2), dim3(256), 0, stream>>>(timg, tmsk, ipw, ipb, mpw, mpb, aib, amb);
  attbias<<<dim3(HW_ / 256, B_), dim3(256), 0, stream>>>(aib, amb, alpha, beta, A1b, asdb, bsdb);
  // MFMA attention partials + combine
  attn_mfma<<<dim3(4, NH_, B_), dim3(256), 0, stream>>>(qbuf, kbuf, vbuf, masks, A1b, asdb, bsdb,
                                                        cw, cb, pacc, pmb, plb);
  attn_comb<<<dim3(B_ * Q_ * E_ / 256), dim3(256), 0, stream>>>(pacc, pmb, plb, ctx);
  // final projection
  row_gemm256<false><<<dim3(B_ * Q_), dim3(256), 0, stream>>>(ctx, nullptr, nullptr, ow, ob, (float*)d_out);
}